// Round 6
// baseline (179.252 us; speedup 1.0000x reference)
//
#include <hip/hip_runtime.h>
#include <hip/hip_bf16.h>

#define NB 2
#define SEQ 2048
#define DM 384
#define NH 8
#define HD 48
#define QKVN 1152
#define BH (NB*NH)

typedef __hip_bfloat16 bf16;
typedef __attribute__((ext_vector_type(8))) short short8;
typedef __attribute__((ext_vector_type(4))) float float4v;

static __device__ __forceinline__ float bf2f(bf16 v){ return __bfloat162float(v); }
static __device__ __forceinline__ float ldin(const void* p, size_t i, int isf){
    return isf ? ((const float*)p)[i] : bf2f(((const bf16*)p)[i]);
}
// fp32 -> bf16 bits, RNE
static __device__ __forceinline__ short f2b(float f){
    union { float f; unsigned u; } a; a.f = f;
    unsigned r = a.u + 0x7FFFu + ((a.u >> 16) & 1u);
    return (short)(r >> 16);
}
static __device__ __forceinline__ unsigned pk2(float a, float b){
    union { float f; unsigned u; } ua, ub; ua.f = a; ub.f = b;
    return ((ua.u + 0x8000u) >> 16) | ((ub.u + 0x8000u) & 0xFFFF0000u);
}
static __device__ __forceinline__ float bflo(unsigned u){
    union { unsigned u; float f; } a; a.u = u << 16; return a.f;
}
static __device__ __forceinline__ float bfhi(unsigned u){
    union { unsigned u; float f; } a; a.u = u & 0xFFFF0000u; return a.f;
}
// per-block input dtype probe (0 = bf16, 1 = fp32); wave-uniform, all waves agree
static __device__ __forceinline__ int detect_isf(const void* x){
    const unsigned short* xb = (const unsigned short*)x;
    int l = threadIdx.x & 63;
    union { unsigned u; float f; } a; a.u = ((unsigned)xb[2*l]) << 16;
    float ab = fabsf(a.f);
    int good = (a.f == 0.0f) || (ab > 9.765625e-4f && ab < 1024.0f);
    unsigned long long m = __ballot(good);
    return (__popcll(m) >= 32) ? 0 : 1;
}

// ---------------- K_prep: dist8 + xb + WqT/WoT + biases + wdist (all dtype-normalized)
// sections: [0,512) dist | [512,1280) xb | [1280,1712) WqT | [1712,1856) WoT | [1856,1863) misc
__global__ __launch_bounds__(256) void k_prep(const void* __restrict__ x,
    const void* __restrict__ coords,
    const void* __restrict__ Wqkv, const void* __restrict__ Wout,
    const void* __restrict__ bqkv, const void* __restrict__ bout,
    const void* __restrict__ Wdist, const void* __restrict__ bdist,
    short* __restrict__ dist8, short* __restrict__ xb,
    short* __restrict__ WqT, short* __restrict__ WoT,
    float* __restrict__ bqf, float* __restrict__ bof,
    float* __restrict__ wdf, float* __restrict__ bdf)
{
    const int isf = detect_isf(x);
    const int t = threadIdx.x;
    const int b = blockIdx.x;
    if (b < 512) {
        const int bb = b >> 8;
        const int j0 = (b & 255) * 8;
        __shared__ float cjx[8], cjy[8], cjz[8];
        if (t < 8) {
            int gj = (bb*SEQ + j0 + t)*3;
            cjx[t] = ldin(coords, gj, isf);
            cjy[t] = ldin(coords, gj+1, isf);
            cjz[t] = ldin(coords, gj+2, isf);
        }
        __syncthreads();
        #pragma unroll
        for (int ii = 0; ii < 8; ++ii) {
            int i = ii*256 + t;
            int gi = (bb*SEQ + i)*3;
            float px = ldin(coords, gi, isf), py = ldin(coords, gi+1, isf), pz = ldin(coords, gi+2, isf);
            short o[8];
            #pragma unroll
            for (int e = 0; e < 8; ++e) {
                float dx = px - cjx[e], dy = py - cjy[e], dz = pz - cjz[e];
                o[e] = f2b(sqrtf(dx*dx + dy*dy + dz*dz));
            }
            *(int4*)(dist8 + ((size_t)b*SEQ + i)*8) = *(const int4*)o;
        }
    } else if (b < 1280) {
        size_t i = ((size_t)(b-512)*256 + t)*8;
        if (isf) {
            const float* xf = (const float*)x + i;
            short o[8];
            #pragma unroll
            for (int e = 0; e < 8; ++e) o[e] = f2b(xf[e]);
            *(int4*)(xb + i) = *(const int4*)o;
        } else {
            *(int4*)(xb + i) = *(const int4*)((const short*)x + i);
        }
    } else if (b < 1856) {
        int bb, NW; const void* W; short* WT;
        if (b < 1712) { bb = b - 1280; NW = QKVN; W = Wqkv; WT = WqT; }
        else          { bb = b - 1712; NW = DM;   W = Wout; WT = WoT; }
        int ntiles = NW >> 5;
        int kt = bb / ntiles, nt = bb % ntiles;
        int k0 = kt*32, n0 = nt*32;
        __shared__ float Ls[32][33];
        for (int idx = t; idx < 1024; idx += 256) {
            int r = idx >> 5, c = idx & 31;
            Ls[r][c] = ldin(W, (size_t)(k0+r)*NW + n0 + c, isf);
        }
        __syncthreads();
        for (int idx = t; idx < 1024; idx += 256) {
            int r2 = idx >> 5, c2 = idx & 31;
            WT[(size_t)(n0+r2)*DM + k0 + c2] = f2b(Ls[c2][r2]);
        }
    } else {
        int idx = (b - 1856)*256 + t;
        if (idx < QKVN) bqf[idx] = ldin(bqkv, idx, isf);
        else if (idx < QKVN + DM) bof[idx - QKVN] = ldin(bout, idx - QKVN, isf);
        else if (idx < QKVN + DM + NH) wdf[idx - QKVN - DM] = ldin(Wdist, idx - QKVN - DM, isf);
        else if (idx < QKVN + DM + 2*NH) bdf[idx - QKVN - DM - NH] = ldin(bdist, idx - QKVN - DM - NH, isf);
    }
}

// ---------------- K1: MFMA GEMM qkv = xb @ Wqkv + b; LDS-coalesced frag-linear scatter
__global__ __launch_bounds__(256) void k_qkv(const short* __restrict__ xb,
    const short* __restrict__ WT, const float* __restrict__ bias,
    short* __restrict__ qg2, short* __restrict__ kg2, short* __restrict__ vg2)
{
    __shared__ __align__(16) short As[64*72];
    __shared__ __align__(16) short Bs[128*72];   // reused as epilogue buffer
    const int t = threadIdx.x;
    const int w = t >> 6, lane = t & 63, L = lane & 15, quad = lane >> 4;
    const int mt = blockIdx.x / 9, nt = blockIdx.x % 9;
    const int row0 = mt*64, col0 = nt*128;
    const int wm = w & 1, wn = w >> 1;
    float4v acc[2][4] = {};
    for (int k0 = 0; k0 < DM; k0 += 64) {
        __syncthreads();
        for (int c = t; c < 512; c += 256) {
            int row = c >> 3, k8 = c & 7;
            *(int4*)(&As[row*72 + k8*8]) = *(const int4*)(xb + (size_t)(row0+row)*DM + k0 + k8*8);
        }
        for (int c = t; c < 1024; c += 256) {
            int row = c >> 3, k8 = c & 7;
            *(int4*)(&Bs[row*72 + k8*8]) = *(const int4*)(WT + (size_t)(col0+row)*DM + k0 + k8*8);
        }
        __syncthreads();
        #pragma unroll
        for (int kc = 0; kc < 2; ++kc) {
            short8 a0 = *(const short8*)(&As[(32*wm + L)*72 + kc*32 + quad*8]);
            short8 a1 = *(const short8*)(&As[(32*wm + 16 + L)*72 + kc*32 + quad*8]);
            #pragma unroll
            for (int ni = 0; ni < 4; ++ni) {
                short8 bf = *(const short8*)(&Bs[(64*wn + 16*ni + L)*72 + kc*32 + quad*8]);
                acc[0][ni] = __builtin_amdgcn_mfma_f32_16x16x32_bf16(a0, bf, acc[0][ni], 0, 0, 0);
                acc[1][ni] = __builtin_amdgcn_mfma_f32_16x16x32_bf16(a1, bf, acc[1][ni], 0, 0, 0);
            }
        }
    }
    // ---- epilogue: bias add, bf16, LDS transpose, coalesced int4 stores
    const int which = col0 / DM;     // uniform per block
    const int cbase = col0 % DM;
    short* Ep = Bs;
    __syncthreads();
    if (which < 2) {
        // row-major Ep[64][136]
        #pragma unroll
        for (int mi = 0; mi < 2; ++mi)
            #pragma unroll
            for (int ni = 0; ni < 4; ++ni) {
                int col_l = 64*wn + 16*ni + L;
                float bv = bias[col0 + col_l];
                #pragma unroll
                for (int r = 0; r < 4; ++r) {
                    int row_l = 32*wm + 16*mi + quad*4 + r;
                    Ep[row_l*136 + col_l] = f2b(acc[mi][ni][r] + bv);
                }
            }
        __syncthreads();
        short* dst = which ? kg2 : qg2;
        for (int c = t; c < 1024; c += 256) {
            int row_l = c >> 4, col_l = (c & 15)*8;
            int4 val = *(const int4*)(&Ep[row_l*136 + col_l]);
            int row_g = row0 + row_l;
            int bi = row_g >> 11, nn = row_g & (SEQ-1);
            int c2 = cbase + col_l;
            int hh = c2/HD, dd = c2%HD;
            int bh = bi*NH + hh;
            size_t u = ((((size_t)bh*128 + (nn>>4))*2 + (dd>>5))*4 + ((dd>>3)&3))*128
                       + (size_t)(nn & 15)*8;
            *(int4*)(dst + u) = val;
        }
    } else {
        // col-major Ep[128][72]
        #pragma unroll
        for (int mi = 0; mi < 2; ++mi)
            #pragma unroll
            for (int ni = 0; ni < 4; ++ni) {
                int col_l = 64*wn + 16*ni + L;
                float bv = bias[col0 + col_l];
                #pragma unroll
                for (int r = 0; r < 4; ++r) {
                    int row_l = 32*wm + 16*mi + quad*4 + r;
                    Ep[col_l*72 + row_l] = f2b(acc[mi][ni][r] + bv);
                }
            }
        __syncthreads();
        for (int c = t; c < 1024; c += 256) {
            int col_l = c >> 3, row_l = (c & 7)*8;
            int4 val = *(const int4*)(&Ep[col_l*72 + row_l]);
            int row_g = row0 + row_l;
            int bi = row_g >> 11, nn = row_g & (SEQ-1);
            int c2 = cbase + col_l;
            int hh = c2/HD, dd = c2%HD;
            int bh = bi*NH + hh;
            size_t u = (((((size_t)bh*32 + (nn>>6))*3 + (dd>>4))*2 + ((nn>>5)&1))*4 + ((nn>>3)&3))*128
                       + (size_t)(dd & 15)*8;
            *(int4*)(vg2 + u) = val;
        }
    }
}

// ---------------- K2: MFMA flash attention, S^T form, register-double-buffered
__global__ __launch_bounds__(256) void k_attn(
    const short* __restrict__ qg2, const short* __restrict__ kg2, const short* __restrict__ vg2,
    const short* __restrict__ dist8, const float* __restrict__ wdf,
    const float* __restrict__ bdf, float* __restrict__ partO, float* __restrict__ partL)
{
    __shared__ __align__(16) short PsT[4][16*72];
    const int t = threadIdx.x;
    const int w = t >> 6, lane = t & 63, L = lane & 15, q = lane >> 4;
    const int bid = blockIdx.x;
    const int jsb = bid & 1, it = (bid >> 1) & 31, bh = bid >> 6;
    const int bi = bh >> 3, hh = bh & 7;
    const int i0 = it*64;
    const float scale = 0.14433756729740643f;   // 1/sqrt(48)
    const float wd = wdf[hh], bd = bdf[hh];

    const short* qbase = qg2 + (((size_t)bh*128 + it*4 + w)*2)*512;
    const short8 qa0 = *(const short8*)(qbase + (q*16 + L)*8);
    const short8 qa1 = *(const short8*)(qbase + 512 + (q*16 + L)*8);

    const int iL = i0 + 16*w + L;
    float rsum = 0.f;
    float4v accO[3] = {};

    const short* kB = kg2 + (size_t)bh*131072 + (q*16 + L)*8;
    const short* vB = vg2 + (size_t)bh*98304  + (q*16 + L)*8;
    const short* dB = dist8 + (size_t)bi*256*SEQ*8 + (size_t)iL*8 + 4*(q&1);

    const int jlo = jsb*(SEQ/2), jhi = jlo + SEQ/2;

    short8 pk[2][8];
    uint2  pd[2][4];
    #pragma unroll
    for (int nt = 0; nt < 4; ++nt) {                  // preload iter 0
        const short* kb = kB + (size_t)((jlo>>4) + nt)*1024;
        pk[0][nt*2]   = *(const short8*)(kb);
        pk[0][nt*2+1] = *(const short8*)(kb + 512);
        pd[0][nt] = *(const uint2*)(dB + (size_t)((jlo>>3) + 2*nt + (q>>1))*(SEQ*8));
    }

    #pragma unroll 2
    for (int j0 = jlo; j0 < jhi; j0 += 64) {
        const int p = (j0 >> 6) & 1;                  // jlo is a multiple of 128 -> starts at parity 0
        const int jn = (j0 + 64 < jhi) ? j0 + 64 : jlo;
        // prefetch next-iter K + dist
        #pragma unroll
        for (int nt = 0; nt < 4; ++nt) {
            const short* kb = kB + (size_t)((jn>>4) + nt)*1024;
            pk[p^1][nt*2]   = *(const short8*)(kb);
            pk[p^1][nt*2+1] = *(const short8*)(kb + 512);
            pd[p^1][nt] = *(const uint2*)(dB + (size_t)((jn>>3) + 2*nt + (q>>1))*(SEQ*8));
        }
        // V loads for current iter (consumed ~250 cyc later)
        short8 vf[6];
        #pragma unroll
        for (int dt = 0; dt < 3; ++dt) {
            const short* vb = vB + (size_t)((j0>>6)*3 + dt)*1024;
            vf[dt*2]   = *(const short8*)(vb);
            vf[dt*2+1] = *(const short8*)(vb + 512);
        }
        // S^T = K Q^T
        float4v sacc[4] = {};
        #pragma unroll
        for (int nt = 0; nt < 4; ++nt) {
            sacc[nt] = __builtin_amdgcn_mfma_f32_16x16x32_bf16(pk[p][nt*2],   qa0, sacc[nt], 0, 0, 0);
            sacc[nt] = __builtin_amdgcn_mfma_f32_16x16x32_bf16(pk[p][nt*2+1], qa1, sacc[nt], 0, 0, 0);
        }
        // logits -> p -> PsT
        #pragma unroll
        for (int nt = 0; nt < 4; ++nt) {
            uint2 du = pd[p][nt];
            float d0 = bflo(du.x), d1 = bfhi(du.x), d2 = bflo(du.y), d3 = bfhi(du.y);
            float p0 = __expf(fmaf(sacc[nt][0], scale, fmaf(d0, wd, bd)));
            float p1 = __expf(fmaf(sacc[nt][1], scale, fmaf(d1, wd, bd)));
            float p2 = __expf(fmaf(sacc[nt][2], scale, fmaf(d2, wd, bd)));
            float p3 = __expf(fmaf(sacc[nt][3], scale, fmaf(d3, wd, bd)));
            rsum += (p0 + p1) + (p2 + p3);
            uint2 pw; pw.x = pk2(p0, p1); pw.y = pk2(p2, p3);
            *(uint2*)(&PsT[w][L*72 + 16*nt + 4*q]) = pw;
        }
        // P A-frags (same-wave RAW; compiler inserts lgkmcnt wait)
        short8 pa0 = *(const short8*)(&PsT[w][L*72 + q*8]);
        short8 pa1 = *(const short8*)(&PsT[w][L*72 + 32 + q*8]);
        #pragma unroll
        for (int dt = 0; dt < 3; ++dt) {
            accO[dt] = __builtin_amdgcn_mfma_f32_16x16x32_bf16(pa0, vf[dt*2],   accO[dt], 0, 0, 0);
            accO[dt] = __builtin_amdgcn_mfma_f32_16x16x32_bf16(pa1, vf[dt*2+1], accO[dt], 0, 0, 0);
        }
    }
    rsum += __shfl_xor(rsum, 16);
    rsum += __shfl_xor(rsum, 32);
    const size_t pbase = ((size_t)(jsb*BH + bh))*SEQ;
    if (q == 0) partL[pbase + iL] = rsum;
    #pragma unroll
    for (int dt = 0; dt < 3; ++dt)
        #pragma unroll
        for (int r = 0; r < 4; ++r)
            partO[(pbase + i0 + 16*w + 4*q + r)*48 + 16*dt + L] = accO[dt][r];
}

// ---------------- K_red: aob = (sum_js partO) / (sum_js partL), bf16
__global__ __launch_bounds__(256) void k_red(const float* __restrict__ partO,
    const float* __restrict__ partL, short* __restrict__ aob)
{
    int g = blockIdx.x*256 + threadIdx.x;
    int row = g / 48, cg = g % 48;
    int bi = row >> 11, i = row & (SEQ-1);
    int hh = cg / 6, d8 = (cg % 6)*8;
    int bh = bi*NH + hh;
    size_t o0 = ((size_t)bh*SEQ + i)*48 + d8;
    size_t o1 = ((size_t)(BH + bh)*SEQ + i)*48 + d8;
    float4 a0 = *(const float4*)(partO + o0);
    float4 a1 = *(const float4*)(partO + o0 + 4);
    float4 b0 = *(const float4*)(partO + o1);
    float4 b1 = *(const float4*)(partO + o1 + 4);
    float l = partL[(size_t)bh*SEQ + i] + partL[(size_t)(BH + bh)*SEQ + i];
    float inv = 1.0f / l;
    short o[8];
    o[0] = f2b((a0.x + b0.x)*inv); o[1] = f2b((a0.y + b0.y)*inv);
    o[2] = f2b((a0.z + b0.z)*inv); o[3] = f2b((a0.w + b0.w)*inv);
    o[4] = f2b((a1.x + b1.x)*inv); o[5] = f2b((a1.y + b1.y)*inv);
    o[6] = f2b((a1.z + b1.z)*inv); o[7] = f2b((a1.w + b1.w)*inv);
    *(int4*)(aob + (size_t)row*DM + hh*HD + d8) = *(const int4*)o;
}

// ---------------- K3: MFMA GEMM out = aob @ Wout + b_out
__global__ __launch_bounds__(256) void k_out(const short* __restrict__ aob,
    const short* __restrict__ WT, const float* __restrict__ bias,
    void* __restrict__ out, const void* __restrict__ x)
{
    __shared__ __align__(16) short As[64*72];
    __shared__ __align__(16) short Bs[128*72];
    const int isf = detect_isf(x);
    const int t = threadIdx.x;
    const int w = t >> 6, lane = t & 63, L = lane & 15, quad = lane >> 4;
    const int mt = blockIdx.x / 3, nt = blockIdx.x % 3;
    const int row0 = mt*64, col0 = nt*128;
    const int wm = w & 1, wn = w >> 1;
    float4v acc[2][4] = {};
    for (int k0 = 0; k0 < DM; k0 += 64) {
        __syncthreads();
        for (int c = t; c < 512; c += 256) {
            int row = c >> 3, k8 = c & 7;
            *(int4*)(&As[row*72 + k8*8]) = *(const int4*)(aob + (size_t)(row0+row)*DM + k0 + k8*8);
        }
        for (int c = t; c < 1024; c += 256) {
            int row = c >> 3, k8 = c & 7;
            *(int4*)(&Bs[row*72 + k8*8]) = *(const int4*)(WT + (size_t)(col0+row)*DM + k0 + k8*8);
        }
        __syncthreads();
        #pragma unroll
        for (int kc = 0; kc < 2; ++kc) {
            short8 a0 = *(const short8*)(&As[(32*wm + L)*72 + kc*32 + quad*8]);
            short8 a1 = *(const short8*)(&As[(32*wm + 16 + L)*72 + kc*32 + quad*8]);
            #pragma unroll
            for (int ni = 0; ni < 4; ++ni) {
                short8 bf = *(const short8*)(&Bs[(64*wn + 16*ni + L)*72 + kc*32 + quad*8]);
                acc[0][ni] = __builtin_amdgcn_mfma_f32_16x16x32_bf16(a0, bf, acc[0][ni], 0, 0, 0);
                acc[1][ni] = __builtin_amdgcn_mfma_f32_16x16x32_bf16(a1, bf, acc[1][ni], 0, 0, 0);
            }
        }
    }
    #pragma unroll
    for (int mi = 0; mi < 2; ++mi) {
        #pragma unroll
        for (int ni = 0; ni < 4; ++ni) {
            int col_g = col0 + 64*wn + 16*ni + L;
            float bv = bias[col_g];
            #pragma unroll
            for (int r = 0; r < 4; ++r) {
                int row_g = row0 + 32*wm + 16*mi + quad*4 + r;
                size_t oi = (size_t)row_g*DM + col_g;
                float val = acc[mi][ni][r] + bv;
                if (isf) ((float*)out)[oi] = val;
                else     ((bf16*)out)[oi]  = __float2bfloat16(val);
            }
        }
    }
}

extern "C" void kernel_launch(void* const* d_in, const int* in_sizes, int n_in,
                              void* d_out, int out_size, void* d_ws, size_t ws_size,
                              hipStream_t stream) {
    const void* x      = d_in[0];
    const void* coords = d_in[1];
    const void* Wqkv   = d_in[2];
    const void* bqkv   = d_in[3];
    const void* Wdist  = d_in[4];
    const void* bdist  = d_in[5];
    const void* Wout   = d_in[6];
    const void* bout   = d_in[7];

    short* qg2   = (short*)d_ws;                       // frag-linear q
    short* kg2   = qg2  + (size_t)2097152;
    short* vg2   = kg2  + (size_t)2097152;
    short* dist8 = vg2  + (size_t)1572864;             // 16 MB bf16
    short* aob   = dist8 + (size_t)8388608;
    short* xb    = aob  + (size_t)1572864;
    short* WqT   = xb   + (size_t)1572864;
    short* WoT   = WqT  + (size_t)442368;
    float* partO = (float*)(WoT + (size_t)147456);
    float* partL = partO + (size_t)3145728;
    float* bqf   = partL + (size_t)65536;
    float* bof   = bqf + QKVN;
    float* wdf   = bof + DM;
    float* bdf   = wdf + NH;

    // zero q/k fragment buffers (d=48..63 pads must be 0)
    hipMemsetAsync(qg2, 0, (size_t)2*2097152*sizeof(short), stream);

    k_prep<<<dim3(1863), dim3(256), 0, stream>>>(x, coords, Wqkv, Wout, bqkv, bout,
                                                 Wdist, bdist, dist8, xb, WqT, WoT,
                                                 bqf, bof, wdf, bdf);
    k_qkv<<<dim3(64*9), dim3(256), 0, stream>>>(xb, WqT, bqf, qg2, kg2, vg2);
    k_attn<<<dim3(1024), dim3(256), 0, stream>>>(qg2, kg2, vg2, dist8, wdf, bdf,
                                                 partO, partL);
    k_red<<<dim3(768), dim3(256), 0, stream>>>(partO, partL, aob);
    k_out<<<dim3(64*3), dim3(256), 0, stream>>>(aob, WoT, bof, d_out, x);
}

// Round 7
// 165.841 us; speedup vs baseline: 1.0809x; 1.0809x over previous
//
#include <hip/hip_runtime.h>
#include <hip/hip_bf16.h>

#define NB 2
#define SEQ 2048
#define DM 384
#define NH 8
#define HD 48
#define QKVN 1152
#define BH (NB*NH)
#define NSPLIT 4

typedef __hip_bfloat16 bf16;
typedef __attribute__((ext_vector_type(8))) short short8;
typedef __attribute__((ext_vector_type(4))) float float4v;

static __device__ __forceinline__ float bf2f(bf16 v){ return __bfloat162float(v); }
static __device__ __forceinline__ float ldin(const void* p, size_t i, int isf){
    return isf ? ((const float*)p)[i] : bf2f(((const bf16*)p)[i]);
}
// fp32 -> bf16 bits, RNE
static __device__ __forceinline__ short f2b(float f){
    union { float f; unsigned u; } a; a.f = f;
    unsigned r = a.u + 0x7FFFu + ((a.u >> 16) & 1u);
    return (short)(r >> 16);
}
static __device__ __forceinline__ unsigned pk2(float a, float b){
    union { float f; unsigned u; } ua, ub; ua.f = a; ub.f = b;
    return ((ua.u + 0x8000u) >> 16) | ((ub.u + 0x8000u) & 0xFFFF0000u);
}
static __device__ __forceinline__ float bflo(unsigned u){
    union { unsigned u; float f; } a; a.u = u << 16; return a.f;
}
static __device__ __forceinline__ float bfhi(unsigned u){
    union { unsigned u; float f; } a; a.u = u & 0xFFFF0000u; return a.f;
}
static __device__ __forceinline__ float bfs(unsigned short s){
    union { unsigned u; float f; } a; a.u = ((unsigned)s) << 16; return a.f;
}
// per-block input dtype probe (0 = bf16, 1 = fp32); wave-uniform, all waves agree
static __device__ __forceinline__ int detect_isf(const void* x){
    const unsigned short* xb = (const unsigned short*)x;
    int l = threadIdx.x & 63;
    union { unsigned u; float f; } a; a.u = ((unsigned)xb[2*l]) << 16;
    float ab = fabsf(a.f);
    int good = (a.f == 0.0f) || (ab > 9.765625e-4f && ab < 1024.0f);
    unsigned long long m = __ballot(good);
    return (__popcll(m) >= 32) ? 0 : 1;
}

// ---------------- K_prep: dist8 + xb + WqT/WoT + biases + wdist (all dtype-normalized)
__global__ __launch_bounds__(256) void k_prep(const void* __restrict__ x,
    const void* __restrict__ coords,
    const void* __restrict__ Wqkv, const void* __restrict__ Wout,
    const void* __restrict__ bqkv, const void* __restrict__ bout,
    const void* __restrict__ Wdist, const void* __restrict__ bdist,
    short* __restrict__ dist8, short* __restrict__ xb,
    short* __restrict__ WqT, short* __restrict__ WoT,
    float* __restrict__ bqf, float* __restrict__ bof,
    float* __restrict__ wdf, float* __restrict__ bdf)
{
    const int isf = detect_isf(x);
    const int t = threadIdx.x;
    const int b = blockIdx.x;
    if (b < 512) {
        const int bb = b >> 8;
        const int j0 = (b & 255) * 8;
        __shared__ float cjx[8], cjy[8], cjz[8];
        if (t < 8) {
            int gj = (bb*SEQ + j0 + t)*3;
            cjx[t] = ldin(coords, gj, isf);
            cjy[t] = ldin(coords, gj+1, isf);
            cjz[t] = ldin(coords, gj+2, isf);
        }
        __syncthreads();
        #pragma unroll
        for (int ii = 0; ii < 8; ++ii) {
            int i = ii*256 + t;
            int gi = (bb*SEQ + i)*3;
            float px = ldin(coords, gi, isf), py = ldin(coords, gi+1, isf), pz = ldin(coords, gi+2, isf);
            short o[8];
            #pragma unroll
            for (int e = 0; e < 8; ++e) {
                float dx = px - cjx[e], dy = py - cjy[e], dz = pz - cjz[e];
                o[e] = f2b(sqrtf(dx*dx + dy*dy + dz*dz));
            }
            *(int4*)(dist8 + ((size_t)b*SEQ + i)*8) = *(const int4*)o;
        }
    } else if (b < 1280) {
        size_t i = ((size_t)(b-512)*256 + t)*8;
        if (isf) {
            const float* xf = (const float*)x + i;
            short o[8];
            #pragma unroll
            for (int e = 0; e < 8; ++e) o[e] = f2b(xf[e]);
            *(int4*)(xb + i) = *(const int4*)o;
        } else {
            *(int4*)(xb + i) = *(const int4*)((const short*)x + i);
        }
    } else if (b < 1856) {
        int bb, NW; const void* W; short* WT;
        if (b < 1712) { bb = b - 1280; NW = QKVN; W = Wqkv; WT = WqT; }
        else          { bb = b - 1712; NW = DM;   W = Wout; WT = WoT; }
        int ntiles = NW >> 5;
        int kt = bb / ntiles, nt = bb % ntiles;
        int k0 = kt*32, n0 = nt*32;
        __shared__ float Ls[32][33];
        for (int idx = t; idx < 1024; idx += 256) {
            int r = idx >> 5, c = idx & 31;
            Ls[r][c] = ldin(W, (size_t)(k0+r)*NW + n0 + c, isf);
        }
        __syncthreads();
        for (int idx = t; idx < 1024; idx += 256) {
            int r2 = idx >> 5, c2 = idx & 31;
            WT[(size_t)(n0+r2)*DM + k0 + c2] = f2b(Ls[c2][r2]);
        }
    } else {
        int idx = (b - 1856)*256 + t;
        if (idx < QKVN) bqf[idx] = ldin(bqkv, idx, isf);
        else if (idx < QKVN + DM) bof[idx - QKVN] = ldin(bout, idx - QKVN, isf);
        else if (idx < QKVN + DM + NH) wdf[idx - QKVN - DM] = ldin(Wdist, idx - QKVN - DM, isf);
        else if (idx < QKVN + DM + 2*NH) bdf[idx - QKVN - DM - NH] = ldin(bdist, idx - QKVN - DM - NH, isf);
    }
}

// ---------------- K1: MFMA GEMM qkv = xb @ Wqkv + b; LDS-coalesced frag-linear scatter
__global__ __launch_bounds__(256) void k_qkv(const short* __restrict__ xb,
    const short* __restrict__ WT, const float* __restrict__ bias,
    short* __restrict__ qg2, short* __restrict__ kg2, short* __restrict__ vg2)
{
    __shared__ __align__(16) short As[64*72];
    __shared__ __align__(16) short Bs[128*72];   // reused as epilogue buffer
    const int t = threadIdx.x;
    const int w = t >> 6, lane = t & 63, L = lane & 15, quad = lane >> 4;
    const int mt = blockIdx.x / 9, nt = blockIdx.x % 9;
    const int row0 = mt*64, col0 = nt*128;
    const int wm = w & 1, wn = w >> 1;
    float4v acc[2][4] = {};
    for (int k0 = 0; k0 < DM; k0 += 64) {
        __syncthreads();
        for (int c = t; c < 512; c += 256) {
            int row = c >> 3, k8 = c & 7;
            *(int4*)(&As[row*72 + k8*8]) = *(const int4*)(xb + (size_t)(row0+row)*DM + k0 + k8*8);
        }
        for (int c = t; c < 1024; c += 256) {
            int row = c >> 3, k8 = c & 7;
            *(int4*)(&Bs[row*72 + k8*8]) = *(const int4*)(WT + (size_t)(col0+row)*DM + k0 + k8*8);
        }
        __syncthreads();
        #pragma unroll
        for (int kc = 0; kc < 2; ++kc) {
            short8 a0 = *(const short8*)(&As[(32*wm + L)*72 + kc*32 + quad*8]);
            short8 a1 = *(const short8*)(&As[(32*wm + 16 + L)*72 + kc*32 + quad*8]);
            #pragma unroll
            for (int ni = 0; ni < 4; ++ni) {
                short8 bf = *(const short8*)(&Bs[(64*wn + 16*ni + L)*72 + kc*32 + quad*8]);
                acc[0][ni] = __builtin_amdgcn_mfma_f32_16x16x32_bf16(a0, bf, acc[0][ni], 0, 0, 0);
                acc[1][ni] = __builtin_amdgcn_mfma_f32_16x16x32_bf16(a1, bf, acc[1][ni], 0, 0, 0);
            }
        }
    }
    const int which = col0 / DM;
    const int cbase = col0 % DM;
    short* Ep = Bs;
    __syncthreads();
    if (which < 2) {
        #pragma unroll
        for (int mi = 0; mi < 2; ++mi)
            #pragma unroll
            for (int ni = 0; ni < 4; ++ni) {
                int col_l = 64*wn + 16*ni + L;
                float bv = bias[col0 + col_l];
                #pragma unroll
                for (int r = 0; r < 4; ++r) {
                    int row_l = 32*wm + 16*mi + quad*4 + r;
                    Ep[row_l*136 + col_l] = f2b(acc[mi][ni][r] + bv);
                }
            }
        __syncthreads();
        short* dst = which ? kg2 : qg2;
        for (int c = t; c < 1024; c += 256) {
            int row_l = c >> 4, col_l = (c & 15)*8;
            int4 val = *(const int4*)(&Ep[row_l*136 + col_l]);
            int row_g = row0 + row_l;
            int bi = row_g >> 11, nn = row_g & (SEQ-1);
            int c2 = cbase + col_l;
            int hh = c2/HD, dd = c2%HD;
            int bh = bi*NH + hh;
            size_t u = ((((size_t)bh*128 + (nn>>4))*2 + (dd>>5))*4 + ((dd>>3)&3))*128
                       + (size_t)(nn & 15)*8;
            *(int4*)(dst + u) = val;
        }
    } else {
        #pragma unroll
        for (int mi = 0; mi < 2; ++mi)
            #pragma unroll
            for (int ni = 0; ni < 4; ++ni) {
                int col_l = 64*wn + 16*ni + L;
                float bv = bias[col0 + col_l];
                #pragma unroll
                for (int r = 0; r < 4; ++r) {
                    int row_l = 32*wm + 16*mi + quad*4 + r;
                    Ep[col_l*72 + row_l] = f2b(acc[mi][ni][r] + bv);
                }
            }
        __syncthreads();
        for (int c = t; c < 1024; c += 256) {
            int col_l = c >> 3, row_l = (c & 7)*8;
            int4 val = *(const int4*)(&Ep[col_l*72 + row_l]);
            int row_g = row0 + row_l;
            int bi = row_g >> 11, nn = row_g & (SEQ-1);
            int c2 = cbase + col_l;
            int hh = c2/HD, dd = c2%HD;
            int bh = bi*NH + hh;
            size_t u = (((((size_t)bh*32 + (nn>>6))*3 + (dd>>4))*2 + ((nn>>5)&1))*4 + ((nn>>3)&3))*128
                       + (size_t)(dd & 15)*8;
            *(int4*)(vg2 + u) = val;
        }
    }
}

// ---------------- K2: MFMA flash attention, S^T form, no-max softmax, j-split x4
__global__ __launch_bounds__(256, 4) void k_attn(
    const short* __restrict__ qg2, const short* __restrict__ kg2, const short* __restrict__ vg2,
    const short* __restrict__ dist8, const float* __restrict__ wdf,
    const float* __restrict__ bdf, short* __restrict__ partO, float* __restrict__ partL)
{
    __shared__ __align__(16) short PsT[4][16*72];
    const int t = threadIdx.x;
    const int w = t >> 6, lane = t & 63, L = lane & 15, q = lane >> 4;
    const int bid = blockIdx.x;
    const int jsb = bid & 3, it = (bid >> 2) & 31, bh = bid >> 7;
    const int bi = bh >> 3, hh = bh & 7;
    const int i0 = it*64;
    const float scale = 0.14433756729740643f;   // 1/sqrt(48)
    const float wd = wdf[hh], bd = bdf[hh];

    // Q A-frags straight from frag-linear global
    const short* qbase = qg2 + (((size_t)bh*128 + it*4 + w)*2)*512;
    const short8 qa0 = *(const short8*)(qbase + (q*16 + L)*8);
    const short8 qa1 = *(const short8*)(qbase + 512 + (q*16 + L)*8);

    const int iL = i0 + 16*w + L;
    float rsum = 0.f;
    float4v accO[3] = {};

    const size_t kBH = (size_t)bh*131072;
    const size_t vBH = (size_t)bh*98304;
    const size_t dB  = (size_t)bi*256*SEQ*8;

    const int jlo = jsb*(SEQ/NSPLIT), jhi = jlo + SEQ/NSPLIT;
    for (int j0 = jlo; j0 < jhi; j0 += 64) {
        float4v sacc[4] = {};
        #pragma unroll
        for (int nt = 0; nt < 4; ++nt) {
            const short* kb = kg2 + kBH + ((size_t)((j0>>4) + nt))*1024;
            short8 kf0 = *(const short8*)(kb + (q*16 + L)*8);
            sacc[nt] = __builtin_amdgcn_mfma_f32_16x16x32_bf16(kf0, qa0, sacc[nt], 0, 0, 0);
            short8 kf1 = *(const short8*)(kb + 512 + (q*16 + L)*8);
            sacc[nt] = __builtin_amdgcn_mfma_f32_16x16x32_bf16(kf1, qa1, sacc[nt], 0, 0, 0);
        }
        #pragma unroll
        for (int nt = 0; nt < 4; ++nt) {
            const short* dp = dist8 + dB + (((size_t)(j0>>6)*8 + 2*nt + (q>>1))*SEQ + iL)*8 + 4*(q&1);
            uint2 du = *(const uint2*)dp;
            float d0 = bflo(du.x), d1 = bfhi(du.x), d2 = bflo(du.y), d3 = bfhi(du.y);
            float p0 = __expf(fmaf(sacc[nt][0], scale, fmaf(d0, wd, bd)));
            float p1 = __expf(fmaf(sacc[nt][1], scale, fmaf(d1, wd, bd)));
            float p2 = __expf(fmaf(sacc[nt][2], scale, fmaf(d2, wd, bd)));
            float p3 = __expf(fmaf(sacc[nt][3], scale, fmaf(d3, wd, bd)));
            rsum += (p0 + p1) + (p2 + p3);
            uint2 pw; pw.x = pk2(p0, p1); pw.y = pk2(p2, p3);
            *(uint2*)(&PsT[w][L*72 + 16*nt + 4*q]) = pw;
        }
        short8 pa0 = *(const short8*)(&PsT[w][L*72 + q*8]);
        short8 pa1 = *(const short8*)(&PsT[w][L*72 + 32 + q*8]);
        #pragma unroll
        for (int dt = 0; dt < 3; ++dt) {
            const short* vb = vg2 + vBH + ((size_t)(j0>>6)*3 + dt)*1024;
            short8 vf0 = *(const short8*)(vb + (q*16 + L)*8);
            accO[dt] = __builtin_amdgcn_mfma_f32_16x16x32_bf16(pa0, vf0, accO[dt], 0, 0, 0);
            short8 vf1 = *(const short8*)(vb + 512 + (q*16 + L)*8);
            accO[dt] = __builtin_amdgcn_mfma_f32_16x16x32_bf16(pa1, vf1, accO[dt], 0, 0, 0);
        }
    }
    rsum += __shfl_xor(rsum, 16);
    rsum += __shfl_xor(rsum, 32);
    const size_t pbase = ((size_t)(jsb*BH + bh))*SEQ;
    if (q == 0) partL[pbase + iL] = rsum;
    #pragma unroll
    for (int dt = 0; dt < 3; ++dt)
        #pragma unroll
        for (int r = 0; r < 4; ++r)
            partO[(pbase + i0 + 16*w + 4*q + r)*48 + 16*dt + L] = f2b(accO[dt][r]);
}

// ---------------- K_red: aob = (sum_s partO_s) / (sum_s partL_s), bf16
__global__ __launch_bounds__(256) void k_red(const short* __restrict__ partO,
    const float* __restrict__ partL, short* __restrict__ aob)
{
    int g = blockIdx.x*256 + threadIdx.x;       // 4096 rows x 48 chunks
    int row = g / 48, cg = g % 48;
    int bi = row >> 11, i = row & (SEQ-1);
    int hh = cg / 6, d8 = (cg % 6)*8;
    int bh = bi*NH + hh;
    float acc[8] = {};
    float l = 0.f;
    #pragma unroll
    for (int s = 0; s < NSPLIT; ++s) {
        const short* p = partO + ((size_t)(s*BH + bh)*SEQ + i)*48 + d8;
        uint4 u = *(const uint4*)p;
        acc[0] += bflo(u.x); acc[1] += bfhi(u.x);
        acc[2] += bflo(u.y); acc[3] += bfhi(u.y);
        acc[4] += bflo(u.z); acc[5] += bfhi(u.z);
        acc[6] += bflo(u.w); acc[7] += bfhi(u.w);
        l += partL[(size_t)(s*BH + bh)*SEQ + i];
    }
    float inv = 1.0f / l;
    short o[8];
    #pragma unroll
    for (int e = 0; e < 8; ++e) o[e] = f2b(acc[e]*inv);
    *(int4*)(aob + (size_t)row*DM + hh*HD + d8) = *(const int4*)o;
}

// ---------------- K3: MFMA GEMM out = aob @ Wout + b_out
__global__ __launch_bounds__(256) void k_out(const short* __restrict__ aob,
    const short* __restrict__ WT, const float* __restrict__ bias,
    void* __restrict__ out, const void* __restrict__ x)
{
    __shared__ __align__(16) short As[64*72];
    __shared__ __align__(16) short Bs[128*72];
    const int isf = detect_isf(x);
    const int t = threadIdx.x;
    const int w = t >> 6, lane = t & 63, L = lane & 15, quad = lane >> 4;
    const int mt = blockIdx.x / 3, nt = blockIdx.x % 3;
    const int row0 = mt*64, col0 = nt*128;
    const int wm = w & 1, wn = w >> 1;
    float4v acc[2][4] = {};
    for (int k0 = 0; k0 < DM; k0 += 64) {
        __syncthreads();
        for (int c = t; c < 512; c += 256) {
            int row = c >> 3, k8 = c & 7;
            *(int4*)(&As[row*72 + k8*8]) = *(const int4*)(aob + (size_t)(row0+row)*DM + k0 + k8*8);
        }
        for (int c = t; c < 1024; c += 256) {
            int row = c >> 3, k8 = c & 7;
            *(int4*)(&Bs[row*72 + k8*8]) = *(const int4*)(WT + (size_t)(col0+row)*DM + k0 + k8*8);
        }
        __syncthreads();
        #pragma unroll
        for (int kc = 0; kc < 2; ++kc) {
            short8 a0 = *(const short8*)(&As[(32*wm + L)*72 + kc*32 + quad*8]);
            short8 a1 = *(const short8*)(&As[(32*wm + 16 + L)*72 + kc*32 + quad*8]);
            #pragma unroll
            for (int ni = 0; ni < 4; ++ni) {
                short8 bf = *(const short8*)(&Bs[(64*wn + 16*ni + L)*72 + kc*32 + quad*8]);
                acc[0][ni] = __builtin_amdgcn_mfma_f32_16x16x32_bf16(a0, bf, acc[0][ni], 0, 0, 0);
                acc[1][ni] = __builtin_amdgcn_mfma_f32_16x16x32_bf16(a1, bf, acc[1][ni], 0, 0, 0);
            }
        }
    }
    #pragma unroll
    for (int mi = 0; mi < 2; ++mi) {
        #pragma unroll
        for (int ni = 0; ni < 4; ++ni) {
            int col_g = col0 + 64*wn + 16*ni + L;
            float bv = bias[col_g];
            #pragma unroll
            for (int r = 0; r < 4; ++r) {
                int row_g = row0 + 32*wm + 16*mi + quad*4 + r;
                size_t oi = (size_t)row_g*DM + col_g;
                float val = acc[mi][ni][r] + bv;
                if (isf) ((float*)out)[oi] = val;
                else     ((bf16*)out)[oi]  = __float2bfloat16(val);
            }
        }
    }
}

extern "C" void kernel_launch(void* const* d_in, const int* in_sizes, int n_in,
                              void* d_out, int out_size, void* d_ws, size_t ws_size,
                              hipStream_t stream) {
    const void* x      = d_in[0];
    const void* coords = d_in[1];
    const void* Wqkv   = d_in[2];
    const void* bqkv   = d_in[3];
    const void* Wdist  = d_in[4];
    const void* bdist  = d_in[5];
    const void* Wout   = d_in[6];
    const void* bout   = d_in[7];

    short* qg2   = (short*)d_ws;
    short* kg2   = qg2  + (size_t)2097152;
    short* vg2   = kg2  + (size_t)2097152;
    short* dist8 = vg2  + (size_t)1572864;             // 16 MB bf16
    short* aob   = dist8 + (size_t)8388608;
    short* xb    = aob  + (size_t)1572864;
    short* WqT   = xb   + (size_t)1572864;
    short* WoT   = WqT  + (size_t)442368;
    short* partO = WoT  + (size_t)147456;              // NSPLIT*16*2048*48 bf16
    float* partL = (float*)(partO + (size_t)NSPLIT*BH*SEQ*48);
    float* bqf   = partL + (size_t)NSPLIT*BH*SEQ;
    float* bof   = bqf + QKVN;
    float* wdf   = bof + DM;
    float* bdf   = wdf + NH;

    // zero q/k fragment buffers (d=48..63 pads must be 0)
    hipMemsetAsync(qg2, 0, (size_t)2*2097152*sizeof(short), stream);

    k_prep<<<dim3(1863), dim3(256), 0, stream>>>(x, coords, Wqkv, Wout, bqkv, bout,
                                                 Wdist, bdist, dist8, xb, WqT, WoT,
                                                 bqf, bof, wdf, bdf);
    k_qkv<<<dim3(64*9), dim3(256), 0, stream>>>(xb, WqT, bqf, qg2, kg2, vg2);
    k_attn<<<dim3(16*32*NSPLIT), dim3(256), 0, stream>>>(qg2, kg2, vg2, dist8, wdf, bdf,
                                                         partO, partL);
    k_red<<<dim3(768), dim3(256), 0, stream>>>(partO, partL, aob);
    k_out<<<dim3(64*3), dim3(256), 0, stream>>>(aob, WoT, bof, d_out, x);
}

// Round 8
// 165.755 us; speedup vs baseline: 1.0814x; 1.0005x over previous
//
#include <hip/hip_runtime.h>
#include <hip/hip_bf16.h>

#define NB 2
#define SEQ 2048
#define DM 384
#define NH 8
#define HD 48
#define QKVN 1152
#define BH (NB*NH)
#define NSPLIT 4

typedef __hip_bfloat16 bf16;
typedef __attribute__((ext_vector_type(8))) short short8;
typedef __attribute__((ext_vector_type(4))) float float4v;

static __device__ __forceinline__ float bf2f(bf16 v){ return __bfloat162float(v); }
static __device__ __forceinline__ float ldin(const void* p, size_t i, int isf){
    return isf ? ((const float*)p)[i] : bf2f(((const bf16*)p)[i]);
}
// fp32 -> bf16 bits, RNE
static __device__ __forceinline__ short f2b(float f){
    union { float f; unsigned u; } a; a.f = f;
    unsigned r = a.u + 0x7FFFu + ((a.u >> 16) & 1u);
    return (short)(r >> 16);
}
static __device__ __forceinline__ unsigned pk2(float a, float b){
    union { float f; unsigned u; } ua, ub; ua.f = a; ub.f = b;
    return ((ua.u + 0x8000u) >> 16) | ((ub.u + 0x8000u) & 0xFFFF0000u);
}
static __device__ __forceinline__ float bflo(unsigned u){
    union { unsigned u; float f; } a; a.u = u << 16; return a.f;
}
static __device__ __forceinline__ float bfhi(unsigned u){
    union { unsigned u; float f; } a; a.u = u & 0xFFFF0000u; return a.f;
}
// short4 (int2) -> short8 with zero upper half (k-relabel trick for d=48 / j=16 chunks)
static __device__ __forceinline__ short8 s4z(int2 v){
    union { int2 i; short s[4]; } u; u.i = v;
    short8 r = {u.s[0], u.s[1], u.s[2], u.s[3], 0, 0, 0, 0};
    return r;
}
static __device__ __forceinline__ short8 u2z(unsigned a, unsigned b){
    union { unsigned u[2]; short s[4]; } u0; u0.u[0] = a; u0.u[1] = b;
    short8 r = {u0.s[0], u0.s[1], u0.s[2], u0.s[3], 0, 0, 0, 0};
    return r;
}
// per-block input dtype probe (0 = bf16, 1 = fp32); wave-uniform
static __device__ __forceinline__ int detect_isf(const void* x){
    const unsigned short* xb = (const unsigned short*)x;
    int l = threadIdx.x & 63;
    union { unsigned u; float f; } a; a.u = ((unsigned)xb[2*l]) << 16;
    float ab = fabsf(a.f);
    int good = (a.f == 0.0f) || (ab > 9.765625e-4f && ab < 1024.0f);
    unsigned long long m = __ballot(good);
    return (__popcll(m) >= 32) ? 0 : 1;
}

// ---------------- K_prep
// sections: [0,256) dist | [256,1024) xb | [1024,1456) WqT | [1456,1600) WoT | [1600,1607) misc
// dist8 layout: [b][jg(128)][i(2048)][16 jj] bf16
__global__ __launch_bounds__(256) void k_prep(const void* __restrict__ x,
    const void* __restrict__ coords,
    const void* __restrict__ Wqkv, const void* __restrict__ Wout,
    const void* __restrict__ bqkv, const void* __restrict__ bout,
    const void* __restrict__ Wdist, const void* __restrict__ bdist,
    short* __restrict__ dist8, short* __restrict__ xb,
    short* __restrict__ WqT, short* __restrict__ WoT,
    float* __restrict__ bqf, float* __restrict__ bof,
    float* __restrict__ wdf, float* __restrict__ bdf)
{
    const int isf = detect_isf(x);
    const int t = threadIdx.x;
    const int b = blockIdx.x;
    if (b < 256) {
        const int bb = b >> 7;               // batch
        const int j0 = (b & 127) * 16;
        __shared__ float cjx[16], cjy[16], cjz[16];
        if (t < 16) {
            int gj = (bb*SEQ + j0 + t)*3;
            cjx[t] = ldin(coords, gj, isf);
            cjy[t] = ldin(coords, gj+1, isf);
            cjz[t] = ldin(coords, gj+2, isf);
        }
        __syncthreads();
        #pragma unroll
        for (int k = 0; k < 8; ++k) {
            int i = k*256 + t;
            int gi = (bb*SEQ + i)*3;
            float px = ldin(coords, gi, isf), py = ldin(coords, gi+1, isf), pz = ldin(coords, gi+2, isf);
            short o[16];
            #pragma unroll
            for (int e = 0; e < 16; ++e) {
                float dx = px - cjx[e], dy = py - cjy[e], dz = pz - cjz[e];
                o[e] = f2b(sqrtf(dx*dx + dy*dy + dz*dz));
            }
            short* dst = dist8 + ((size_t)b*SEQ + i)*16;
            *(int4*)dst       = *(const int4*)(o);
            *(int4*)(dst + 8) = *(const int4*)(o + 8);
        }
    } else if (b < 1024) {
        size_t i = ((size_t)(b-256)*256 + t)*8;
        if (isf) {
            const float* xf = (const float*)x + i;
            short o[8];
            #pragma unroll
            for (int e = 0; e < 8; ++e) o[e] = f2b(xf[e]);
            *(int4*)(xb + i) = *(const int4*)o;
        } else {
            *(int4*)(xb + i) = *(const int4*)((const short*)x + i);
        }
    } else if (b < 1600) {
        int bb, NW; const void* W; short* WT;
        if (b < 1456) { bb = b - 1024; NW = QKVN; W = Wqkv; WT = WqT; }
        else          { bb = b - 1456; NW = DM;   W = Wout; WT = WoT; }
        int ntiles = NW >> 5;
        int kt = bb / ntiles, nt = bb % ntiles;
        int k0 = kt*32, n0 = nt*32;
        __shared__ float Ls[32][33];
        for (int idx = t; idx < 1024; idx += 256) {
            int r = idx >> 5, c = idx & 31;
            Ls[r][c] = ldin(W, (size_t)(k0+r)*NW + n0 + c, isf);
        }
        __syncthreads();
        for (int idx = t; idx < 1024; idx += 256) {
            int r2 = idx >> 5, c2 = idx & 31;
            WT[(size_t)(n0+r2)*DM + k0 + c2] = f2b(Ls[c2][r2]);
        }
    } else {
        int idx = (b - 1600)*256 + t;
        const float log2e = 1.4426950408889634f;
        if (idx < QKVN) bqf[idx] = ldin(bqkv, idx, isf);
        else if (idx < QKVN + DM) bof[idx - QKVN] = ldin(bout, idx - QKVN, isf);
        else if (idx < QKVN + DM + NH) wdf[idx - QKVN - DM] = ldin(Wdist, idx - QKVN - DM, isf)*log2e;
        else if (idx < QKVN + DM + 2*NH) bdf[idx - QKVN - DM - NH] = ldin(bdist, idx - QKVN - DM - NH, isf)*log2e;
    }
}

// ---------------- K1: MFMA GEMM qkv = xb @ Wqkv + b; scatter to 48-d frag-linear layouts
// qg2/kg2: [bh][tile16][ chunk0: (q)(L)(8)  | +512 chunk1: (q')(L)(4) ]  (768 shorts/tile)
// vg2:     [bh][tile16][dt(3)][(q)(L)(4)]                                (768 shorts/tile)
__global__ __launch_bounds__(256) void k_qkv(const short* __restrict__ xb,
    const short* __restrict__ WT, const float* __restrict__ bias,
    short* __restrict__ qg2, short* __restrict__ kg2, short* __restrict__ vg2)
{
    __shared__ __align__(16) short As[64*72];
    __shared__ __align__(16) short Bs[128*72];   // reused as epilogue buffer
    const int t = threadIdx.x;
    const int w = t >> 6, lane = t & 63, L = lane & 15, quad = lane >> 4;
    const int mt = blockIdx.x / 9, nt = blockIdx.x % 9;
    const int row0 = mt*64, col0 = nt*128;
    const int wm = w & 1, wn = w >> 1;
    float4v acc[2][4] = {};
    for (int k0 = 0; k0 < DM; k0 += 64) {
        __syncthreads();
        for (int c = t; c < 512; c += 256) {
            int row = c >> 3, k8 = c & 7;
            *(int4*)(&As[row*72 + k8*8]) = *(const int4*)(xb + (size_t)(row0+row)*DM + k0 + k8*8);
        }
        for (int c = t; c < 1024; c += 256) {
            int row = c >> 3, k8 = c & 7;
            *(int4*)(&Bs[row*72 + k8*8]) = *(const int4*)(WT + (size_t)(col0+row)*DM + k0 + k8*8);
        }
        __syncthreads();
        #pragma unroll
        for (int kc = 0; kc < 2; ++kc) {
            short8 a0 = *(const short8*)(&As[(32*wm + L)*72 + kc*32 + quad*8]);
            short8 a1 = *(const short8*)(&As[(32*wm + 16 + L)*72 + kc*32 + quad*8]);
            #pragma unroll
            for (int ni = 0; ni < 4; ++ni) {
                short8 bf = *(const short8*)(&Bs[(64*wn + 16*ni + L)*72 + kc*32 + quad*8]);
                acc[0][ni] = __builtin_amdgcn_mfma_f32_16x16x32_bf16(a0, bf, acc[0][ni], 0, 0, 0);
                acc[1][ni] = __builtin_amdgcn_mfma_f32_16x16x32_bf16(a1, bf, acc[1][ni], 0, 0, 0);
            }
        }
    }
    const int which = col0 / DM;     // uniform per block (0=q,1=k,2=v)
    const int cbase = col0 % DM;
    short* Ep = Bs;
    __syncthreads();
    if (which < 2) {
        // row-major Ep[64 tokens][136]
        #pragma unroll
        for (int mi = 0; mi < 2; ++mi)
            #pragma unroll
            for (int ni = 0; ni < 4; ++ni) {
                int col_l = 64*wn + 16*ni + L;
                float bv = bias[col0 + col_l];
                #pragma unroll
                for (int r = 0; r < 4; ++r) {
                    int row_l = 32*wm + 16*mi + quad*4 + r;
                    Ep[row_l*136 + col_l] = f2b(acc[mi][ni][r] + bv);
                }
            }
        __syncthreads();
        short* dst = which ? kg2 : qg2;
        for (int c = t; c < 1024; c += 256) {
            int row_l = c >> 4, col_l = (c & 15)*8;   // 8 consecutive d for one token
            int row_g = row0 + row_l;
            int bi = row_g >> 11, nn = row_g & (SEQ-1);
            int c2 = cbase + col_l;
            int hh = c2/HD, dh = c2%HD;
            int bh = bi*NH + hh;
            size_t base = ((size_t)bh*128 + (nn>>4))*768;
            int Ltok = nn & 15;
            const short* src = &Ep[row_l*136 + col_l];
            if (dh < 32) {
                *(int4*)(dst + base + (dh>>3)*128 + Ltok*8) = *(const int4*)src;
            } else {
                int q0 = (dh - 32) >> 2;
                *(int2*)(dst + base + 512 + q0*64     + Ltok*4) = *(const int2*)src;
                *(int2*)(dst + base + 512 + (q0+1)*64 + Ltok*4) = *(const int2*)(src + 4);
            }
        }
    } else {
        // col-major Ep[128 cols][72 tokens]
        #pragma unroll
        for (int mi = 0; mi < 2; ++mi)
            #pragma unroll
            for (int ni = 0; ni < 4; ++ni) {
                int col_l = 64*wn + 16*ni + L;
                float bv = bias[col0 + col_l];
                #pragma unroll
                for (int r = 0; r < 4; ++r) {
                    int row_l = 32*wm + 16*mi + quad*4 + r;
                    Ep[col_l*72 + row_l] = f2b(acc[mi][ni][r] + bv);
                }
            }
        __syncthreads();
        for (int c = t; c < 1024; c += 256) {
            int col_l = c >> 3, row8 = (c & 7)*8;     // 8 consecutive tokens, one d
            int row_g = row0 + row8;
            int bi = row_g >> 11, nn = row_g & (SEQ-1);
            int c2 = cbase + col_l;
            int hh = c2/HD, dh = c2%HD;
            int bh = bi*NH + hh;
            int dt = dh >> 4, Lh = dh & 15;
            size_t base3 = (((size_t)bh*128 + (nn>>4))*3 + dt)*256;
            int q0 = (nn & 15) >> 2;                  // nn multiple of 8 -> q0 in {0,2}
            const short* src = &Ep[col_l*72 + row8];
            *(int2*)(vg2 + base3 + q0*64     + Lh*4) = *(const int2*)src;
            *(int2*)(vg2 + base3 + (q0+1)*64 + Lh*4) = *(const int2*)(src + 4);
        }
    }
}

// ---------------- K2: flash attention; wave = 16 j-rows x 64 i; zero LDS in loop
__global__ __launch_bounds__(256, 3) void k_attn(
    const short* __restrict__ qg2, const short* __restrict__ kg2, const short* __restrict__ vg2,
    const short* __restrict__ dist8, const float* __restrict__ wdf,
    const float* __restrict__ bdf, short* __restrict__ partO, float* __restrict__ partL)
{
    __shared__ float Ored[2][64*48];
    __shared__ float Lred[2][64];
    const int t = threadIdx.x;
    const int w = t >> 6, lane = t & 63, L = lane & 15, q = lane >> 4;
    const int bid = blockIdx.x;
    const int jsb = bid & 3, it = (bid >> 2) & 31, bh = bid >> 7;
    const int bi = bh >> 3, hh = bh & 7;
    const int i0 = it*64;
    const float scale2 = 0.14433756729740643f * 1.4426950408889634f;
    const float wd = wdf[hh], bd = bdf[hh];     // pre-scaled by log2e

    // Q fragments (held all loop): 4 i-tiles x (chunk0 b128 + chunk1 b64-zeroext)
    const short* qB = qg2 + ((size_t)bh*128 + it*4)*768;
    short8 qa0[4], qa1[4];
    #pragma unroll
    for (int nt = 0; nt < 4; ++nt) {
        qa0[nt] = *(const short8*)(qB + nt*768 + q*128 + L*8);
        qa1[nt] = s4z(*(const int2*)(qB + nt*768 + 512 + q*64 + L*4));
    }

    float4v accO[4][3] = {};
    float rsum[4] = {};

    const short* kBp = kg2 + ((size_t)bh*128 + jsb*32 + w)*768;
    const short* vBp = vg2 + ((size_t)bh*128 + jsb*32 + w)*768;
    const short* dBp = dist8 + (((size_t)bi*128 + jsb*32 + w)*SEQ + i0 + L)*16 + 4*q;

    #pragma unroll 2
    for (int itr = 0; itr < SEQ/NSPLIT/64; ++itr) {
        short8 ka0 = *(const short8*)(kBp + q*128 + L*8);
        short8 ka1 = s4z(*(const int2*)(kBp + 512 + q*64 + L*4));
        float4v sacc[4] = {};
        #pragma unroll
        for (int nt = 0; nt < 4; ++nt) {
            sacc[nt] = __builtin_amdgcn_mfma_f32_16x16x32_bf16(ka0, qa0[nt], sacc[nt], 0, 0, 0);
            sacc[nt] = __builtin_amdgcn_mfma_f32_16x16x32_bf16(ka1, qa1[nt], sacc[nt], 0, 0, 0);
        }
        short8 vf[3];
        #pragma unroll
        for (int dt = 0; dt < 3; ++dt)
            vf[dt] = s4z(*(const int2*)(vBp + dt*256 + q*64 + L*4));
        short8 pa[4];
        #pragma unroll
        for (int nt = 0; nt < 4; ++nt) {
            int2 du = *(const int2*)(dBp + nt*256);
            float d0 = bflo((unsigned)du.x), d1 = bfhi((unsigned)du.x);
            float d2 = bflo((unsigned)du.y), d3 = bfhi((unsigned)du.y);
            float p0 = __builtin_amdgcn_exp2f(fmaf(sacc[nt][0], scale2, fmaf(d0, wd, bd)));
            float p1 = __builtin_amdgcn_exp2f(fmaf(sacc[nt][1], scale2, fmaf(d1, wd, bd)));
            float p2 = __builtin_amdgcn_exp2f(fmaf(sacc[nt][2], scale2, fmaf(d2, wd, bd)));
            float p3 = __builtin_amdgcn_exp2f(fmaf(sacc[nt][3], scale2, fmaf(d3, wd, bd)));
            rsum[nt] += (p0 + p1) + (p2 + p3);
            pa[nt] = u2z(pk2(p0, p1), pk2(p2, p3));
        }
        #pragma unroll
        for (int nt = 0; nt < 4; ++nt)
            #pragma unroll
            for (int dt = 0; dt < 3; ++dt)
                accO[nt][dt] = __builtin_amdgcn_mfma_f32_16x16x32_bf16(pa[nt], vf[dt], accO[nt][dt], 0, 0, 0);
        kBp += 4*768; vBp += 4*768; dBp += (size_t)4*SEQ*16;
    }
    // row-sums (over this wave's 16 j) -> all lanes hold sum for i = 16nt+L
    #pragma unroll
    for (int nt = 0; nt < 4; ++nt) {
        rsum[nt] += __shfl_xor(rsum[nt], 16);
        rsum[nt] += __shfl_xor(rsum[nt], 32);
    }
    // cross-wave tree reduction (4 waves -> wave 0)
    if (w >= 2) {
        float* Od = Ored[w-2];
        #pragma unroll
        for (int mt = 0; mt < 4; ++mt)
            #pragma unroll
            for (int dt = 0; dt < 3; ++dt)
                #pragma unroll
                for (int r = 0; r < 4; ++r)
                    Od[(16*mt + 4*q + r)*48 + 16*dt + L] = accO[mt][dt][r];
        if (q == 0)
            #pragma unroll
            for (int nt = 0; nt < 4; ++nt) Lred[w-2][16*nt + L] = rsum[nt];
    }
    __syncthreads();
    if (w < 2) {
        float* Od = Ored[w];
        #pragma unroll
        for (int mt = 0; mt < 4; ++mt)
            #pragma unroll
            for (int dt = 0; dt < 3; ++dt)
                #pragma unroll
                for (int r = 0; r < 4; ++r)
                    accO[mt][dt][r] += Od[(16*mt + 4*q + r)*48 + 16*dt + L];
        #pragma unroll
        for (int nt = 0; nt < 4; ++nt) rsum[nt] += Lred[w][16*nt + L];
    }
    __syncthreads();
    if (w == 1) {
        float* Od = Ored[0];
        #pragma unroll
        for (int mt = 0; mt < 4; ++mt)
            #pragma unroll
            for (int dt = 0; dt < 3; ++dt)
                #pragma unroll
                for (int r = 0; r < 4; ++r)
                    Od[(16*mt + 4*q + r)*48 + 16*dt + L] = accO[mt][dt][r];
        if (q == 0)
            #pragma unroll
            for (int nt = 0; nt < 4; ++nt) Lred[0][16*nt + L] = rsum[nt];
    }
    __syncthreads();
    if (w == 0) {
        float* Od = Ored[0];
        const size_t pbase = ((size_t)(jsb*BH + bh))*SEQ;
        #pragma unroll
        for (int mt = 0; mt < 4; ++mt)
            #pragma unroll
            for (int dt = 0; dt < 3; ++dt)
                #pragma unroll
                for (int r = 0; r < 4; ++r) {
                    float v = accO[mt][dt][r] + Od[(16*mt + 4*q + r)*48 + 16*dt + L];
                    partO[(pbase + i0 + 16*mt + 4*q + r)*48 + 16*dt + L] = f2b(v);
                }
        if (q == 0)
            #pragma unroll
            for (int nt = 0; nt < 4; ++nt)
                partL[pbase + i0 + 16*nt + L] = rsum[nt] + Lred[0][16*nt + L];
    }
}

// ---------------- K_red: aob = (sum_s partO_s) / (sum_s partL_s), bf16
__global__ __launch_bounds__(256) void k_red(const short* __restrict__ partO,
    const float* __restrict__ partL, short* __restrict__ aob)
{
    int g = blockIdx.x*256 + threadIdx.x;
    int row = g / 48, cg = g % 48;
    int bi = row >> 11, i = row & (SEQ-1);
    int hh = cg / 6, d8 = (cg % 6)*8;
    int bh = bi*NH + hh;
    float acc[8] = {};
    float l = 0.f;
    #pragma unroll
    for (int s = 0; s < NSPLIT; ++s) {
        const short* p = partO + ((size_t)(s*BH + bh)*SEQ + i)*48 + d8;
        uint4 u = *(const uint4*)p;
        acc[0] += bflo(u.x); acc[1] += bfhi(u.x);
        acc[2] += bflo(u.y); acc[3] += bfhi(u.y);
        acc[4] += bflo(u.z); acc[5] += bfhi(u.z);
        acc[6] += bflo(u.w); acc[7] += bfhi(u.w);
        l += partL[(size_t)(s*BH + bh)*SEQ + i];
    }
    float inv = 1.0f / l;
    short o[8];
    #pragma unroll
    for (int e = 0; e < 8; ++e) o[e] = f2b(acc[e]*inv);
    *(int4*)(aob + (size_t)row*DM + hh*HD + d8) = *(const int4*)o;
}

// ---------------- K3: MFMA GEMM out = aob @ Wout + b_out
__global__ __launch_bounds__(256) void k_out(const short* __restrict__ aob,
    const short* __restrict__ WT, const float* __restrict__ bias,
    void* __restrict__ out, const void* __restrict__ x)
{
    __shared__ __align__(16) short As[64*72];
    __shared__ __align__(16) short Bs[128*72];
    const int isf = detect_isf(x);
    const int t = threadIdx.x;
    const int w = t >> 6, lane = t & 63, L = lane & 15, quad = lane >> 4;
    const int mt = blockIdx.x / 3, nt = blockIdx.x % 3;
    const int row0 = mt*64, col0 = nt*128;
    const int wm = w & 1, wn = w >> 1;
    float4v acc[2][4] = {};
    for (int k0 = 0; k0 < DM; k0 += 64) {
        __syncthreads();
        for (int c = t; c < 512; c += 256) {
            int row = c >> 3, k8 = c & 7;
            *(int4*)(&As[row*72 + k8*8]) = *(const int4*)(aob + (size_t)(row0+row)*DM + k0 + k8*8);
        }
        for (int c = t; c < 1024; c += 256) {
            int row = c >> 3, k8 = c & 7;
            *(int4*)(&Bs[row*72 + k8*8]) = *(const int4*)(WT + (size_t)(col0+row)*DM + k0 + k8*8);
        }
        __syncthreads();
        #pragma unroll
        for (int kc = 0; kc < 2; ++kc) {
            short8 a0 = *(const short8*)(&As[(32*wm + L)*72 + kc*32 + quad*8]);
            short8 a1 = *(const short8*)(&As[(32*wm + 16 + L)*72 + kc*32 + quad*8]);
            #pragma unroll
            for (int ni = 0; ni < 4; ++ni) {
                short8 bf = *(const short8*)(&Bs[(64*wn + 16*ni + L)*72 + kc*32 + quad*8]);
                acc[0][ni] = __builtin_amdgcn_mfma_f32_16x16x32_bf16(a0, bf, acc[0][ni], 0, 0, 0);
                acc[1][ni] = __builtin_amdgcn_mfma_f32_16x16x32_bf16(a1, bf, acc[1][ni], 0, 0, 0);
            }
        }
    }
    #pragma unroll
    for (int mi = 0; mi < 2; ++mi) {
        #pragma unroll
        for (int ni = 0; ni < 4; ++ni) {
            int col_g = col0 + 64*wn + 16*ni + L;
            float bv = bias[col_g];
            #pragma unroll
            for (int r = 0; r < 4; ++r) {
                int row_g = row0 + 32*wm + 16*mi + quad*4 + r;
                size_t oi = (size_t)row_g*DM + col_g;
                float val = acc[mi][ni][r] + bv;
                if (isf) ((float*)out)[oi] = val;
                else     ((bf16*)out)[oi]  = __float2bfloat16(val);
            }
        }
    }
}

extern "C" void kernel_launch(void* const* d_in, const int* in_sizes, int n_in,
                              void* d_out, int out_size, void* d_ws, size_t ws_size,
                              hipStream_t stream) {
    const void* x      = d_in[0];
    const void* coords = d_in[1];
    const void* Wqkv   = d_in[2];
    const void* bqkv   = d_in[3];
    const void* Wdist  = d_in[4];
    const void* bdist  = d_in[5];
    const void* Wout   = d_in[6];
    const void* bout   = d_in[7];

    short* qg2   = (short*)d_ws;                       // 16*128*768 = 1,572,864
    short* kg2   = qg2  + (size_t)1572864;
    short* vg2   = kg2  + (size_t)1572864;
    short* dist8 = vg2  + (size_t)1572864;             // 2*128*2048*16 = 8,388,608
    short* aob   = dist8 + (size_t)8388608;
    short* xb    = aob  + (size_t)1572864;
    short* WqT   = xb   + (size_t)1572864;
    short* WoT   = WqT  + (size_t)442368;
    short* partO = WoT  + (size_t)147456;              // 4*16*2048*48 = 6,291,456
    float* partL = (float*)(partO + (size_t)6291456);  // 131,072 floats
    float* bqf   = partL + (size_t)131072;
    float* bof   = bqf + QKVN;
    float* wdf   = bof + DM;
    float* bdf   = wdf + NH;

    k_prep<<<dim3(1607), dim3(256), 0, stream>>>(x, coords, Wqkv, Wout, bqkv, bout,
                                                 Wdist, bdist, dist8, xb, WqT, WoT,
                                                 bqf, bof, wdf, bdf);
    k_qkv<<<dim3(64*9), dim3(256), 0, stream>>>(xb, WqT, bqf, qg2, kg2, vg2);
    k_attn<<<dim3(16*32*NSPLIT), dim3(256), 0, stream>>>(qg2, kg2, vg2, dist8, wdf, bdf,
                                                         partO, partL);
    k_red<<<dim3(768), dim3(256), 0, stream>>>(partO, partL, aob);
    k_out<<<dim3(64*3), dim3(256), 0, stream>>>(aob, WoT, bof, d_out, x);
}